// Round 2
// baseline (491.054 us; speedup 1.0000x reference)
//
#include <hip/hip_runtime.h>
#include <cmath>

#define D_K 768
#define GK 640
#define KC_N 24   // 768/32 k-chunks
#define NC_N 40   // 640/16 n-chunks

typedef _Float16 f16x8 __attribute__((ext_vector_type(8)));
typedef float f32x4 __attribute__((ext_vector_type(4)));

// ---------------- prep: zero bins + swizzle W (fp32 -> fp16 hi/lo, MFMA B-frag order) ----------------
// WH/WL layout: [kc][nc][lane][j] halves; lane supplies B[k = kc*32 + (lane>>4)*8 + j][n = nc*16 + (lane&15)]
__global__ __launch_bounds__(256) void prep_kernel(const float* __restrict__ W,
        unsigned* __restrict__ bins, _Float16* __restrict__ WH, _Float16* __restrict__ WL) {
    int t = blockIdx.x * 256 + threadIdx.x;   // 240*256 = 61440 = 960 frags * 64 lanes
    if (t < 1280) bins[t] = 0u;               // counts[640] u32 + probsum[640] f32 (0 bits)
    int fid = t >> 6;
    int l = t & 63;
    int kc = fid / NC_N, nc = fid - kc * NC_N;
    int n = nc * 16 + (l & 15);
    int k0 = kc * 32 + (l >> 4) * 8;
    f16x8 hi, lo;
#pragma unroll
    for (int j = 0; j < 8; ++j) {
        float wv = W[(size_t)(k0 + j) * GK + n];
        _Float16 h = (_Float16)wv;
        hi[j] = h;
        lo[j] = (_Float16)(wv - (float)h);    // exact residual, then RTN to fp16
    }
    *(f16x8*)(WH + (size_t)fid * 512 + l * 8) = hi;
    *(f16x8*)(WL + (size_t)fid * 512 + l * 8) = lo;
}

// ---------------- main: fused GEMM (fp16x2, 3-product) + argmax/softmax/gumbel + gather ----------------
// block = 64 rows x 640 cols; 8 waves; wave w: nc in [w*5, w*5+5), mc 0..3 (all 64 rows); group g = w>>2
__global__ __launch_bounds__(512) void main_kernel(
        const float* __restrict__ x, const float* __restrict__ bias,
        const float* __restrict__ noise, const float* __restrict__ cb,
        const _Float16* __restrict__ WH, const _Float16* __restrict__ WL,
        float* __restrict__ out, unsigned* __restrict__ counts, float* __restrict__ probsum)
{
    int tid = threadIdx.x;
    int w = tid >> 6;
    int l = tid & 63;
    int lrow = l >> 4;       // quad 0..3
    int lcol = l & 15;
    int r0 = blockIdx.x * 64;
    int ncb = w * 5;
    int g = w >> 2;

    f32x4 acc[4][5];
#pragma unroll
    for (int mc = 0; mc < 4; ++mc)
#pragma unroll
        for (int j = 0; j < 5; ++j) acc[mc][j] = (f32x4){0.f, 0.f, 0.f, 0.f};

    // A: lane l holds A[m = lane&15][k = quad*8 + j]; row = r0 + mc*16 + lcol
    const float* xb = x + (size_t)(r0 + lcol) * D_K + lrow * 8;

    for (int kc = 0; kc < KC_N; ++kc) {
        f16x8 ah[4], al[4];
#pragma unroll
        for (int mc = 0; mc < 4; ++mc) {
            const float* p = xb + mc * (16 * D_K) + kc * 32;
            f32x4 v0 = *(const f32x4*)p;
            f32x4 v1 = *(const f32x4*)(p + 4);
#pragma unroll
            for (int j = 0; j < 4; ++j) {
                float f0 = v0[j];
                _Float16 h0 = (_Float16)f0;
                ah[mc][j] = h0; al[mc][j] = (_Float16)(f0 - (float)h0);
                float f1 = v1[j];
                _Float16 h1 = (_Float16)f1;
                ah[mc][4 + j] = h1; al[mc][4 + j] = (_Float16)(f1 - (float)h1);
            }
        }
        const _Float16* bh_p = WH + ((size_t)(kc * NC_N + ncb) * 64 + l) * 8;
        const _Float16* bl_p = WL + ((size_t)(kc * NC_N + ncb) * 64 + l) * 8;
#pragma unroll
        for (int j = 0; j < 5; ++j) {
            f16x8 bh = *(const f16x8*)(bh_p + j * 512);
            f16x8 bl = *(const f16x8*)(bl_p + j * 512);
#pragma unroll
            for (int mc = 0; mc < 4; ++mc) {
                acc[mc][j] = __builtin_amdgcn_mfma_f32_16x16x32_f16(ah[mc], bh, acc[mc][j], 0, 0, 0);
                acc[mc][j] = __builtin_amdgcn_mfma_f32_16x16x32_f16(al[mc], bh, acc[mc][j], 0, 0, 0);
                acc[mc][j] = __builtin_amdgcn_mfma_f32_16x16x32_f16(ah[mc], bl, acc[mc][j], 0, 0, 0);
            }
        }
    }

    // bias (zeros in setup, but keep it correct)
#pragma unroll
    for (int j = 0; j < 5; ++j) {
        float bb = bias[(ncb + j) * 16 + lcol];
#pragma unroll
        for (int mc = 0; mc < 4; ++mc)
#pragma unroll
            for (int r = 0; r < 4; ++r) acc[mc][j][r] += bb;
    }

    // ---------------- epilogue ----------------
    __shared__ float s_pmax[8][64];
    __shared__ int   s_pcol[8][64];
    __shared__ float s_pgmax[8][64];
    __shared__ int   s_pgcol[8][64];
    __shared__ float s_psum[8][64];
    __shared__ float s_fmax[128];
    __shared__ float s_fsum[128];
    __shared__ int   s_fgcol[128];
    __shared__ float s_bins[640];

    // E1: per-wave partial (max,argmax) of logits and of logits+gumbel over this wave's 80-col slice
#pragma unroll
    for (int mc = 0; mc < 4; ++mc) {
#pragma unroll
        for (int r = 0; r < 4; ++r) {
            int row = mc * 16 + lrow * 4 + r;   // C/D: row = quad*4 + reg, col = lane&15
            float vmax = -3.4e38f; int vcol = 0;
            float gmax = -3.4e38f; int gcol = 0;
            const float* np = noise + (size_t)(r0 + row) * GK + ncb * 16 + lcol;
#pragma unroll
            for (int j = 0; j < 5; ++j) {
                float v = acc[mc][j][r];
                int c = (ncb + j) * 16 + lcol;
                if (v > vmax) { vmax = v; vcol = c; }
                float u = np[j * 16] * (1.0f - 2e-6f) + 1e-6f;
                float gn = -__logf(-__logf(u));
                float z = v + gn;   // argmax((logits+g)/TAU) == argmax(logits+g)
                if (z > gmax) { gmax = z; gcol = c; }
            }
#pragma unroll
            for (int off = 1; off < 16; off <<= 1) {
                float ov = __shfl_xor(vmax, off); int oc = __shfl_xor(vcol, off);
                if (ov > vmax || (ov == vmax && oc < vcol)) { vmax = ov; vcol = oc; }
                float og = __shfl_xor(gmax, off); int ogc = __shfl_xor(gcol, off);
                if (og > gmax || (og == gmax && ogc < gcol)) { gmax = og; gcol = ogc; }
            }
            if (lcol == 0) {
                s_pmax[w][row] = vmax; s_pcol[w][row] = vcol;
                s_pgmax[w][row] = gmax; s_pgcol[w][row] = gcol;
            }
        }
    }
    // zero 640 bins with 512 threads (two phases!)
    s_bins[tid] = 0.0f;
    if (tid < 128) s_bins[512 + tid] = 0.0f;
    __syncthreads();

    // E2: combine 4 waves per (group,row); hard-count atomic; keep gumbel winner
    if (tid < 128) {
        int gg = tid >> 6, row = tid & 63;
        float vmax = -3.4e38f; int vcol = 0;
        float gmax = -3.4e38f; int gcol = 0;
        for (int ww = gg * 4; ww < gg * 4 + 4; ++ww) {   // ascending cols => first-wins tie rule
            float v = s_pmax[ww][row];
            if (v > vmax) { vmax = v; vcol = s_pcol[ww][row]; }
            float z = s_pgmax[ww][row];
            if (z > gmax) { gmax = z; gcol = s_pgcol[ww][row]; }
        }
        s_fmax[tid] = vmax;
        s_fgcol[tid] = gcol;
        atomicAdd(&counts[vcol], 1u);   // vcol is absolute col = g*320 + k
    }
    __syncthreads();

    // E3: exp-sum per (group,row)
#pragma unroll
    for (int mc = 0; mc < 4; ++mc) {
#pragma unroll
        for (int r = 0; r < 4; ++r) {
            int row = mc * 16 + lrow * 4 + r;
            float M = s_fmax[g * 64 + row];
            float s = 0.f;
#pragma unroll
            for (int j = 0; j < 5; ++j) s += __expf(acc[mc][j][r] - M);
#pragma unroll
            for (int off = 1; off < 16; off <<= 1) s += __shfl_xor(s, off);
            if (lcol == 0) s_psum[w][row] = s;
        }
    }
    __syncthreads();
    if (tid < 128) {
        int gg = tid >> 6, row = tid & 63;
        float S = 0.f;
        for (int ww = gg * 4; ww < gg * 4 + 4; ++ww) S += s_psum[ww][row];
        s_fsum[tid] = S;
    }
    __syncthreads();

    // E4: accumulate softmax probs into LDS bins, then one global atomic per bin
#pragma unroll
    for (int mc = 0; mc < 4; ++mc) {
#pragma unroll
        for (int r = 0; r < 4; ++r) {
            int row = mc * 16 + lrow * 4 + r;
            float M = s_fmax[g * 64 + row];
            float invS = 1.0f / s_fsum[g * 64 + row];
#pragma unroll
            for (int j = 0; j < 5; ++j)
                atomicAdd(&s_bins[(ncb + j) * 16 + lcol], __expf(acc[mc][j][r] - M) * invS);
        }
    }
    __syncthreads();
    // flush 640 bins with 512 threads (two phases — was the round-1 bug)
    atomicAdd(&probsum[tid], s_bins[tid]);
    if (tid < 128) atomicAdd(&probsum[512 + tid], s_bins[512 + tid]);

    // E5: out[row, g*128:(g+1)*128] = cb[winner, :]  (y == y_hard in forward)
    {
        int team = tid >> 2, jj = tid & 3;       // 128 teams of 4 threads
        int row = team >> 1, gg = team & 1;
        int wcol = s_fgcol[gg * 64 + row];       // absolute col => cb flat row index
        const f32x4* src = (const f32x4*)(cb + (size_t)wcol * 128);
        f32x4* dst = (f32x4*)(out + (size_t)(r0 + row) * 256 + gg * 128);
#pragma unroll
        for (int i = 0; i < 8; ++i) dst[i * 4 + jj] = src[i * 4 + jj];
    }
}

// ---------------- finalize: perplexities ----------------
__global__ __launch_bounds__(640) void fin_kernel(const unsigned* __restrict__ counts,
        const float* __restrict__ probsum, float* __restrict__ out2) {
    __shared__ float sh[640], sp[640];
    int t = threadIdx.x;
    float ph = (float)counts[t] * (1.0f / 32768.0f);
    sh[t] = ph * logf(ph + 1e-7f);
    float pp = probsum[t] * (1.0f / 32768.0f);
    sp[t] = pp * logf(pp + 1e-7f);
    __syncthreads();
    if (t < 2) {
        const float* s = (t == 0) ? sh : sp;
        float e0 = 0.f, e1 = 0.f;
        for (int k = 0; k < 320; ++k) { e0 += s[k]; e1 += s[320 + k]; }
        out2[t] = expf(-e0) + expf(-e1);   // sum over groups of exp(-entropy)
    }
}

extern "C" void kernel_launch(void* const* d_in, const int* in_sizes, int n_in,
                              void* d_out, int out_size, void* d_ws, size_t ws_size,
                              hipStream_t stream) {
    const float* x     = (const float*)d_in[0];   // [16,2048,768]
    const float* W     = (const float*)d_in[1];   // [768,640]
    const float* b     = (const float*)d_in[2];   // [640]
    const float* cb    = (const float*)d_in[3];   // [1,640,128]
    const float* noise = (const float*)d_in[4];   // [32768,2,320]
    float* out = (float*)d_out;                   // 16*2048*256 floats + 2 scalars

    char* ws = (char*)d_ws;
    unsigned* counts = (unsigned*)ws;             // [640] u32
    float* probsum   = (float*)(ws + 2560);       // [640] f32
    _Float16* WH     = (_Float16*)(ws + 8192);            // 24*40*64*8 halves = 983040 B
    _Float16* WL     = (_Float16*)(ws + 8192 + 983040);

    hipLaunchKernelGGL(prep_kernel, dim3(240), dim3(256), 0, stream, W, counts, WH, WL);
    hipLaunchKernelGGL(main_kernel, dim3(512), dim3(512), 0, stream,
                       x, b, noise, cb, WH, WL, out, counts, probsum);
    hipLaunchKernelGGL(fin_kernel, dim3(1), dim3(640), 0, stream, counts, probsum, out + 8388608);
}

// Round 3
// 490.542 us; speedup vs baseline: 1.0010x; 1.0010x over previous
//
#include <hip/hip_runtime.h>
#include <cmath>

#define D_K 768
#define GK 640
#define KC_N 24   // 768/32 k-chunks
#define NC_N 40   // 640/16 n-chunks

typedef _Float16 f16x8 __attribute__((ext_vector_type(8)));
typedef float f32x4 __attribute__((ext_vector_type(4)));

// ---------------- prep: zero bins + swizzle W (fp32 -> fp16 hi/lo, MFMA B-frag order) ----------------
// WH/WL layout: [kc][nc][lane][j] halves; lane supplies B[k = kc*32 + (lane>>4)*8 + j][n = nc*16 + (lane&15)]
__global__ __launch_bounds__(256) void prep_kernel(const float* __restrict__ W,
        unsigned* __restrict__ bins, _Float16* __restrict__ WH, _Float16* __restrict__ WL) {
    int t = blockIdx.x * 256 + threadIdx.x;   // 240*256 = 61440 = 960 frags * 64 lanes
    if (t < 1280) bins[t] = 0u;               // counts[640] u32 + probsum[640] f32 (0 bits)
    int fid = t >> 6;
    int l = t & 63;
    int kc = fid / NC_N, nc = fid - kc * NC_N;
    int n = nc * 16 + (l & 15);
    int k0 = kc * 32 + (l >> 4) * 8;
    f16x8 hi, lo;
#pragma unroll
    for (int j = 0; j < 8; ++j) {
        float wv = W[(size_t)(k0 + j) * GK + n];
        _Float16 h = (_Float16)wv;
        hi[j] = h;
        lo[j] = (_Float16)(wv - (float)h);
    }
    *(f16x8*)(WH + (size_t)fid * 512 + l * 8) = hi;
    *(f16x8*)(WL + (size_t)fid * 512 + l * 8) = lo;
}

// ---------------- main: 64 rows x 640 cols per block, 16 waves ----------------
// wave w: m-half mch=w>>3 (rows mch*32..+32, as 2 chunks of 16), nc slice (w&7)*5..+5, group g=(w&7)>>2
// acc = 2x5 f32x4 = 40 VGPR/lane  (round-2's 80-reg acc capped residency at 1 block/CU)
__global__ __launch_bounds__(1024, 4) void main_kernel(
        const float* __restrict__ x, const float* __restrict__ bias,
        const float* __restrict__ noise, const float* __restrict__ cb,
        const _Float16* __restrict__ WH, const _Float16* __restrict__ WL,
        float* __restrict__ out, unsigned* __restrict__ counts, float* __restrict__ probsum)
{
    int tid = threadIdx.x;
    int w = tid >> 6;
    int l = tid & 63;
    int lrow = l >> 4;       // quad 0..3
    int lcol = l & 15;
    int r0 = blockIdx.x * 64;
    int mch = w >> 3;        // 0/1
    int wn = w & 7;
    int ncb = wn * 5;
    int g = wn >> 2;

    f32x4 acc[2][5];
#pragma unroll
    for (int i = 0; i < 2; ++i)
#pragma unroll
        for (int j = 0; j < 5; ++j) acc[i][j] = (f32x4){0.f, 0.f, 0.f, 0.f};

    // A: lane holds A[m=lane&15][k=quad*8+j]; chunk i row = r0 + mch*32 + i*16 + lcol
    const float* xb0 = x + (size_t)(r0 + mch * 32 + lcol) * D_K + lrow * 8;
    const float* xb1 = xb0 + 16 * D_K;

    // A raw double-buffer across kc
    f32x4 a00 = *(const f32x4*)xb0, a01 = *(const f32x4*)(xb0 + 4);
    f32x4 a10 = *(const f32x4*)xb1, a11 = *(const f32x4*)(xb1 + 4);

    for (int kc = 0; kc < KC_N; ++kc) {
        int kn = (kc < KC_N - 1) ? kc + 1 : 0;
        f32x4 n00 = *(const f32x4*)(xb0 + kn * 32), n01 = *(const f32x4*)(xb0 + kn * 32 + 4);
        f32x4 n10 = *(const f32x4*)(xb1 + kn * 32), n11 = *(const f32x4*)(xb1 + kn * 32 + 4);

        f16x8 ah[2], al[2];
#pragma unroll
        for (int j = 0; j < 4; ++j) {
            float f;
            _Float16 h;
            f = a00[j]; h = (_Float16)f; ah[0][j] = h;     al[0][j] = (_Float16)(f - (float)h);
            f = a01[j]; h = (_Float16)f; ah[0][4 + j] = h; al[0][4 + j] = (_Float16)(f - (float)h);
            f = a10[j]; h = (_Float16)f; ah[1][j] = h;     al[1][j] = (_Float16)(f - (float)h);
            f = a11[j]; h = (_Float16)f; ah[1][4 + j] = h; al[1][4 + j] = (_Float16)(f - (float)h);
        }

        const _Float16* bh_p = WH + ((size_t)(kc * NC_N + ncb) * 64 + l) * 8;
        const _Float16* bl_p = WL + ((size_t)(kc * NC_N + ncb) * 64 + l) * 8;
        f16x8 bh = *(const f16x8*)bh_p;
        f16x8 bl = *(const f16x8*)bl_p;
#pragma unroll
        for (int j = 0; j < 5; ++j) {
            int jn = (j < 4) ? j + 1 : 0;
            f16x8 nbh = *(const f16x8*)(bh_p + jn * 512);
            f16x8 nbl = *(const f16x8*)(bl_p + jn * 512);
            acc[0][j] = __builtin_amdgcn_mfma_f32_16x16x32_f16(ah[0], bh, acc[0][j], 0, 0, 0);
            acc[0][j] = __builtin_amdgcn_mfma_f32_16x16x32_f16(al[0], bh, acc[0][j], 0, 0, 0);
            acc[0][j] = __builtin_amdgcn_mfma_f32_16x16x32_f16(ah[0], bl, acc[0][j], 0, 0, 0);
            acc[1][j] = __builtin_amdgcn_mfma_f32_16x16x32_f16(ah[1], bh, acc[1][j], 0, 0, 0);
            acc[1][j] = __builtin_amdgcn_mfma_f32_16x16x32_f16(al[1], bh, acc[1][j], 0, 0, 0);
            acc[1][j] = __builtin_amdgcn_mfma_f32_16x16x32_f16(ah[1], bl, acc[1][j], 0, 0, 0);
            bh = nbh; bl = nbl;
        }
        a00 = n00; a01 = n01; a10 = n10; a11 = n11;
    }

    // bias (zeros in setup, kept for correctness)
#pragma unroll
    for (int j = 0; j < 5; ++j) {
        float bb = bias[(ncb + j) * 16 + lcol];
#pragma unroll
        for (int i = 0; i < 2; ++i)
#pragma unroll
            for (int r = 0; r < 4; ++r) acc[i][j][r] += bb;
    }

    // ---------------- epilogue ----------------
    __shared__ float s_pmax[16][64];
    __shared__ int   s_pcol[16][64];
    __shared__ float s_pgmax[16][64];
    __shared__ int   s_pgcol[16][64];
    __shared__ float s_psum[16][64];
    __shared__ float s_fmax[128];
    __shared__ float s_fsum[128];
    __shared__ int   s_fgcol[128];
    __shared__ float s_bins[640];

    // E1: per-wave partial (max,argmax) of logits and logits+gumbel over this wave's 80-col slice
#pragma unroll
    for (int i = 0; i < 2; ++i) {
#pragma unroll
        for (int r = 0; r < 4; ++r) {
            int row = mch * 32 + i * 16 + lrow * 4 + r;   // C/D: row = quad*4 + reg, col = lane&15
            float vmax = -3.4e38f; int vcol = 0;
            float gmax = -3.4e38f; int gcol = 0;
            const float* np = noise + (size_t)(r0 + row) * GK + ncb * 16 + lcol;
#pragma unroll
            for (int j = 0; j < 5; ++j) {
                float v = acc[i][j][r];
                int c = (ncb + j) * 16 + lcol;
                if (v > vmax) { vmax = v; vcol = c; }
                float u = np[j * 16] * (1.0f - 2e-6f) + 1e-6f;
                float gn = -__logf(-__logf(u));
                float z = v + gn;    // argmax((logits+g)/TAU) == argmax(logits+g)
                if (z > gmax) { gmax = z; gcol = c; }
            }
#pragma unroll
            for (int off = 1; off < 16; off <<= 1) {
                float ov = __shfl_xor(vmax, off); int oc = __shfl_xor(vcol, off);
                if (ov > vmax || (ov == vmax && oc < vcol)) { vmax = ov; vcol = oc; }
                float og = __shfl_xor(gmax, off); int ogc = __shfl_xor(gcol, off);
                if (og > gmax || (og == gmax && ogc < gcol)) { gmax = og; gcol = ogc; }
            }
            if (lcol == 0) {
                s_pmax[w][row] = vmax; s_pcol[w][row] = vcol;
                s_pgmax[w][row] = gmax; s_pgcol[w][row] = gcol;
            }
        }
    }
    if (tid < 640) s_bins[tid] = 0.0f;
    __syncthreads();

    // E2: combine 4 waves per (group,row) in ascending-col order; hard-count atomic; gumbel winner
    if (tid < 128) {
        int gg = tid >> 6, row = tid & 63;
        float vmax = -3.4e38f; int vcol = 0;
        float gmax = -3.4e38f; int gcol = 0;
        int wb = (row >> 5) * 8 + gg * 4;
        for (int i = 0; i < 4; ++i) {
            int ww = wb + i;
            float v = s_pmax[ww][row];
            if (v > vmax) { vmax = v; vcol = s_pcol[ww][row]; }
            float z = s_pgmax[ww][row];
            if (z > gmax) { gmax = z; gcol = s_pgcol[ww][row]; }
        }
        s_fmax[tid] = vmax;
        s_fgcol[tid] = gcol;
        atomicAdd(&counts[vcol], 1u);   // vcol is absolute col = g*320 + k
    }
    __syncthreads();

    // E3: exp-sum per (group,row)
#pragma unroll
    for (int i = 0; i < 2; ++i) {
#pragma unroll
        for (int r = 0; r < 4; ++r) {
            int row = mch * 32 + i * 16 + lrow * 4 + r;
            float M = s_fmax[g * 64 + row];
            float s = 0.f;
#pragma unroll
            for (int j = 0; j < 5; ++j) s += __expf(acc[i][j][r] - M);
#pragma unroll
            for (int off = 1; off < 16; off <<= 1) s += __shfl_xor(s, off);
            if (lcol == 0) s_psum[w][row] = s;
        }
    }
    __syncthreads();
    if (tid < 128) {
        int gg = tid >> 6, row = tid & 63;
        int wb = (row >> 5) * 8 + gg * 4;
        float S = 0.f;
        for (int i = 0; i < 4; ++i) S += s_psum[wb + i][row];
        s_fsum[tid] = S;
    }
    __syncthreads();

    // E4: softmax probs into LDS bins, then one global atomic per bin
#pragma unroll
    for (int i = 0; i < 2; ++i) {
#pragma unroll
        for (int r = 0; r < 4; ++r) {
            int row = mch * 32 + i * 16 + lrow * 4 + r;
            float M = s_fmax[g * 64 + row];
            float invS = 1.0f / s_fsum[g * 64 + row];
#pragma unroll
            for (int j = 0; j < 5; ++j)
                atomicAdd(&s_bins[(ncb + j) * 16 + lcol], __expf(acc[i][j][r] - M) * invS);
        }
    }
    __syncthreads();
    if (tid < 640) atomicAdd(&probsum[tid], s_bins[tid]);

    // E5: out[row, g*128:(g+1)*128] = cb[winner, :]  (y == y_hard in forward)
    {
        int team = tid >> 3, jj = tid & 7;       // 128 teams of 8 threads
        int row = team >> 1, gg = team & 1;
        int wcol = s_fgcol[gg * 64 + row];
        const f32x4* src = (const f32x4*)(cb + (size_t)wcol * 128);
        f32x4* dst = (f32x4*)(out + (size_t)(r0 + row) * 256 + gg * 128);
#pragma unroll
        for (int k = 0; k < 4; ++k) dst[k * 8 + jj] = src[k * 8 + jj];
    }
}

// ---------------- finalize: perplexities (parallel reduction) ----------------
__global__ __launch_bounds__(640) void fin_kernel(const unsigned* __restrict__ counts,
        const float* __restrict__ probsum, float* __restrict__ out2) {
    __shared__ float sh[640], sp[640], sred[4];
    int t = threadIdx.x;
    float ph = (float)counts[t] * (1.0f / 32768.0f);
    sh[t] = ph * logf(ph + 1e-7f);
    float pp = probsum[t] * (1.0f / 32768.0f);
    sp[t] = pp * logf(pp + 1e-7f);
    __syncthreads();
    if (t < 256) {
        int seg = t >> 6;               // 0:sh g0, 1:sh g1, 2:sp g0, 3:sp g1
        int l = t & 63;
        const float* s = (seg & 2) ? sp : sh;
        int base = (seg & 1) * 320;
        float v = 0.f;
#pragma unroll
        for (int k = 0; k < 5; ++k) v += s[base + l + 64 * k];
#pragma unroll
        for (int off = 1; off < 64; off <<= 1) v += __shfl_xor(v, off);
        if (l == 0) sred[seg] = v;
    }
    __syncthreads();
    if (t < 2) out2[t] = expf(-sred[t * 2]) + expf(-sred[t * 2 + 1]);
}

extern "C" void kernel_launch(void* const* d_in, const int* in_sizes, int n_in,
                              void* d_out, int out_size, void* d_ws, size_t ws_size,
                              hipStream_t stream) {
    const float* x     = (const float*)d_in[0];   // [16,2048,768]
    const float* W     = (const float*)d_in[1];   // [768,640]
    const float* b     = (const float*)d_in[2];   // [640]
    const float* cb    = (const float*)d_in[3];   // [1,640,128]
    const float* noise = (const float*)d_in[4];   // [32768,2,320]
    float* out = (float*)d_out;                   // 16*2048*256 floats + 2 scalars

    char* ws = (char*)d_ws;
    unsigned* counts = (unsigned*)ws;             // [640] u32
    float* probsum   = (float*)(ws + 2560);       // [640] f32
    _Float16* WH     = (_Float16*)(ws + 8192);            // 24*40*64*8 halves = 983040 B
    _Float16* WL     = (_Float16*)(ws + 8192 + 983040);

    hipLaunchKernelGGL(prep_kernel, dim3(240), dim3(256), 0, stream, W, counts, WH, WL);
    hipLaunchKernelGGL(main_kernel, dim3(512), dim3(1024), 0, stream,
                       x, b, noise, cb, WH, WL, out, counts, probsum);
    hipLaunchKernelGGL(fin_kernel, dim3(1), dim3(640), 0, stream, counts, probsum, out + 8388608);
}

// Round 4
// 486.561 us; speedup vs baseline: 1.0092x; 1.0082x over previous
//
#include <hip/hip_runtime.h>
#include <cmath>

#define D_K 768
#define GK 640
#define KC_N 24   // 768/32 k-chunks
#define NC_N 40   // 640/16 n-chunks

typedef _Float16 f16x8 __attribute__((ext_vector_type(8)));
typedef float f32x4 __attribute__((ext_vector_type(4)));

// ---------------- prep: zero bins + swizzle W (fp32 -> fp16 hi/lo, MFMA B-frag order) ----------------
// WH/WL layout: [kc][nc][lane][j] halves; lane supplies B[k = kc*32 + (lane>>4)*8 + j][n = nc*16 + (lane&15)]
__global__ __launch_bounds__(256) void prep_kernel(const float* __restrict__ W,
        unsigned* __restrict__ bins, _Float16* __restrict__ WH, _Float16* __restrict__ WL) {
    int t = blockIdx.x * 256 + threadIdx.x;   // 240*256 = 61440 = 960 frags * 64 lanes
    if (t < 1280) bins[t] = 0u;               // counts[640] u32 + probsum[640] f32 (0 bits)
    int fid = t >> 6;
    int l = t & 63;
    int kc = fid / NC_N, nc = fid - kc * NC_N;
    int n = nc * 16 + (l & 15);
    int k0 = kc * 32 + (l >> 4) * 8;
    f16x8 hi, lo;
#pragma unroll
    for (int j = 0; j < 8; ++j) {
        float wv = W[(size_t)(k0 + j) * GK + n];
        _Float16 h = (_Float16)wv;
        hi[j] = h;
        lo[j] = (_Float16)(wv - (float)h);
    }
    *(f16x8*)(WH + (size_t)fid * 512 + l * 8) = hi;
    *(f16x8*)(WL + (size_t)fid * 512 + l * 8) = lo;
}

// ---------------- main: 64 rows x 640 cols per block, 16 waves ----------------
// wave w: m-half mch=w>>3 (2 chunks of 16 rows), nc slice (w&7)*5..+5, group g=(w&7)>>2
// K-loop: all 10 B-frag loads issued at kc top (MLP), A prefetched a full kc ahead.
__global__ __launch_bounds__(1024, 4) void main_kernel(
        const float* __restrict__ x, const float* __restrict__ bias,
        const float* __restrict__ noise, const float* __restrict__ cb,
        const _Float16* __restrict__ WH, const _Float16* __restrict__ WL,
        float* __restrict__ out, unsigned* __restrict__ counts, float* __restrict__ probsum)
{
    int tid = threadIdx.x;
    int w = tid >> 6;
    int l = tid & 63;
    int lrow = l >> 4;       // quad 0..3
    int lcol = l & 15;
    int r0 = blockIdx.x * 64;
    int mch = w >> 3;        // 0/1
    int wn = w & 7;
    int ncb = wn * 5;
    int g = wn >> 2;

    f32x4 acc[2][5];
#pragma unroll
    for (int i = 0; i < 2; ++i)
#pragma unroll
        for (int j = 0; j < 5; ++j) acc[i][j] = (f32x4){0.f, 0.f, 0.f, 0.f};

    // A: lane holds A[m=lane&15][k=quad*8+j]; chunk i row = r0 + mch*32 + i*16 + lcol
    const float* xb0 = x + (size_t)(r0 + mch * 32 + lcol) * D_K + lrow * 8;
    const float* xb1 = xb0 + 16 * D_K;

    // A raw double-buffer across kc (prefetch distance = full kc body)
    f32x4 a00 = *(const f32x4*)xb0, a01 = *(const f32x4*)(xb0 + 4);
    f32x4 a10 = *(const f32x4*)xb1, a11 = *(const f32x4*)(xb1 + 4);

    for (int kc = 0; kc < KC_N; ++kc) {
        // 1) all 10 B-frag loads for THIS kc, issued first (oldest in vm queue ->
        //    waiting on them leaves the A-prefetch in flight)
        const _Float16* bhp = WH + ((size_t)(kc * NC_N + ncb) * 64 + l) * 8;
        const _Float16* blp = WL + ((size_t)(kc * NC_N + ncb) * 64 + l) * 8;
        f16x8 bh[5], bl[5];
#pragma unroll
        for (int j = 0; j < 5; ++j) bh[j] = *(const f16x8*)(bhp + j * 512);
#pragma unroll
        for (int j = 0; j < 5; ++j) bl[j] = *(const f16x8*)(blp + j * 512);

        // 2) A prefetch for next kc (HBM)
        int kn = (kc < KC_N - 1) ? kc + 1 : 0;
        f32x4 n00 = *(const f32x4*)(xb0 + kn * 32), n01 = *(const f32x4*)(xb0 + kn * 32 + 4);
        f32x4 n10 = *(const f32x4*)(xb1 + kn * 32), n11 = *(const f32x4*)(xb1 + kn * 32 + 4);

        // 3) convert current A (VALU work covers B-load latency)
        f16x8 ah[2], al[2];
#pragma unroll
        for (int j = 0; j < 4; ++j) {
            float f;
            _Float16 h;
            f = a00[j]; h = (_Float16)f; ah[0][j] = h;     al[0][j] = (_Float16)(f - (float)h);
            f = a01[j]; h = (_Float16)f; ah[0][4 + j] = h; al[0][4 + j] = (_Float16)(f - (float)h);
            f = a10[j]; h = (_Float16)f; ah[1][j] = h;     al[1][j] = (_Float16)(f - (float)h);
            f = a11[j]; h = (_Float16)f; ah[1][4 + j] = h; al[1][4 + j] = (_Float16)(f - (float)h);
        }

        // 4) MFMA: 3-product fp16x2 (hh + lh + hl)
#pragma unroll
        for (int j = 0; j < 5; ++j) {
            acc[0][j] = __builtin_amdgcn_mfma_f32_16x16x32_f16(ah[0], bh[j], acc[0][j], 0, 0, 0);
            acc[0][j] = __builtin_amdgcn_mfma_f32_16x16x32_f16(al[0], bh[j], acc[0][j], 0, 0, 0);
            acc[0][j] = __builtin_amdgcn_mfma_f32_16x16x32_f16(ah[0], bl[j], acc[0][j], 0, 0, 0);
            acc[1][j] = __builtin_amdgcn_mfma_f32_16x16x32_f16(ah[1], bh[j], acc[1][j], 0, 0, 0);
            acc[1][j] = __builtin_amdgcn_mfma_f32_16x16x32_f16(al[1], bh[j], acc[1][j], 0, 0, 0);
            acc[1][j] = __builtin_amdgcn_mfma_f32_16x16x32_f16(ah[1], bl[j], acc[1][j], 0, 0, 0);
        }
        a00 = n00; a01 = n01; a10 = n10; a11 = n11;
    }

    // bias (zeros in setup, kept for correctness)
#pragma unroll
    for (int j = 0; j < 5; ++j) {
        float bb = bias[(ncb + j) * 16 + lcol];
#pragma unroll
        for (int i = 0; i < 2; ++i)
#pragma unroll
            for (int r = 0; r < 4; ++r) acc[i][j][r] += bb;
    }

    // ---------------- epilogue ----------------
    __shared__ float s_pmax[16][64];
    __shared__ int   s_pcol[16][64];
    __shared__ float s_pgmax[16][64];
    __shared__ int   s_pgcol[16][64];
    __shared__ float s_psum[16][64];
    __shared__ float s_fmax[128];
    __shared__ float s_fsum[128];
    __shared__ int   s_fgcol[128];
    __shared__ float s_bins[640];

    // E1: per-wave partial (max,argmax) of logits and logits+gumbel over this wave's 80-col slice
#pragma unroll
    for (int i = 0; i < 2; ++i) {
#pragma unroll
        for (int r = 0; r < 4; ++r) {
            int row = mch * 32 + i * 16 + lrow * 4 + r;   // C/D: row = quad*4 + reg, col = lane&15
            float vmax = -3.4e38f; int vcol = 0;
            float gmax = -3.4e38f; int gcol = 0;
            const float* np = noise + (size_t)(r0 + row) * GK + ncb * 16 + lcol;
#pragma unroll
            for (int j = 0; j < 5; ++j) {
                float v = acc[i][j][r];
                int c = (ncb + j) * 16 + lcol;
                if (v > vmax) { vmax = v; vcol = c; }
                float u = np[j * 16] * (1.0f - 2e-6f) + 1e-6f;
                float gn = -__logf(-__logf(u));
                float z = v + gn;    // argmax((logits+g)/TAU) == argmax(logits+g)
                if (z > gmax) { gmax = z; gcol = c; }
            }
#pragma unroll
            for (int off = 1; off < 16; off <<= 1) {
                float ov = __shfl_xor(vmax, off); int oc = __shfl_xor(vcol, off);
                if (ov > vmax || (ov == vmax && oc < vcol)) { vmax = ov; vcol = oc; }
                float og = __shfl_xor(gmax, off); int ogc = __shfl_xor(gcol, off);
                if (og > gmax || (og == gmax && ogc < gcol)) { gmax = og; gcol = ogc; }
            }
            if (lcol == 0) {
                s_pmax[w][row] = vmax; s_pcol[w][row] = vcol;
                s_pgmax[w][row] = gmax; s_pgcol[w][row] = gcol;
            }
        }
    }
    if (tid < 640) s_bins[tid] = 0.0f;
    __syncthreads();

    // E2: combine 4 waves per (group,row) in ascending-col order; hard-count atomic; gumbel winner
    if (tid < 128) {
        int gg = tid >> 6, row = tid & 63;
        float vmax = -3.4e38f; int vcol = 0;
        float gmax = -3.4e38f; int gcol = 0;
        int wb = (row >> 5) * 8 + gg * 4;
        for (int i = 0; i < 4; ++i) {
            int ww = wb + i;
            float v = s_pmax[ww][row];
            if (v > vmax) { vmax = v; vcol = s_pcol[ww][row]; }
            float z = s_pgmax[ww][row];
            if (z > gmax) { gmax = z; gcol = s_pgcol[ww][row]; }
        }
        s_fmax[tid] = vmax;
        s_fgcol[tid] = gcol;
        atomicAdd(&counts[vcol], 1u);   // vcol is absolute col = g*320 + k
    }
    __syncthreads();

    // E3: exp-sum per (group,row)
#pragma unroll
    for (int i = 0; i < 2; ++i) {
#pragma unroll
        for (int r = 0; r < 4; ++r) {
            int row = mch * 32 + i * 16 + lrow * 4 + r;
            float M = s_fmax[g * 64 + row];
            float s = 0.f;
#pragma unroll
            for (int j = 0; j < 5; ++j) s += __expf(acc[i][j][r] - M);
#pragma unroll
            for (int off = 1; off < 16; off <<= 1) s += __shfl_xor(s, off);
            if (lcol == 0) s_psum[w][row] = s;
        }
    }
    __syncthreads();
    if (tid < 128) {
        int gg = tid >> 6, row = tid & 63;
        int wb = (row >> 5) * 8 + gg * 4;
        float S = 0.f;
        for (int i = 0; i < 4; ++i) S += s_psum[wb + i][row];
        s_fsum[tid] = S;
    }
    __syncthreads();

    // E4: softmax probs into LDS bins, then one global atomic per bin
#pragma unroll
    for (int i = 0; i < 2; ++i) {
#pragma unroll
        for (int r = 0; r < 4; ++r) {
            int row = mch * 32 + i * 16 + lrow * 4 + r;
            float M = s_fmax[g * 64 + row];
            float invS = 1.0f / s_fsum[g * 64 + row];
#pragma unroll
            for (int j = 0; j < 5; ++j)
                atomicAdd(&s_bins[(ncb + j) * 16 + lcol], __expf(acc[i][j][r] - M) * invS);
        }
    }
    __syncthreads();
    if (tid < 640) atomicAdd(&probsum[tid], s_bins[tid]);

    // E5: out[row, g*128:(g+1)*128] = cb[winner, :]  (y == y_hard in forward)
    {
        int team = tid >> 3, jj = tid & 7;       // 128 teams of 8 threads
        int row = team >> 1, gg = team & 1;
        int wcol = s_fgcol[gg * 64 + row];
        const f32x4* src = (const f32x4*)(cb + (size_t)wcol * 128);
        f32x4* dst = (f32x4*)(out + (size_t)(r0 + row) * 256 + gg * 128);
#pragma unroll
        for (int k = 0; k < 4; ++k) dst[k * 8 + jj] = src[k * 8 + jj];
    }
}

// ---------------- finalize: perplexities (parallel reduction) ----------------
__global__ __launch_bounds__(640) void fin_kernel(const unsigned* __restrict__ counts,
        const float* __restrict__ probsum, float* __restrict__ out2) {
    __shared__ float sh[640], sp[640], sred[4];
    int t = threadIdx.x;
    float ph = (float)counts[t] * (1.0f / 32768.0f);
    sh[t] = ph * logf(ph + 1e-7f);
    float pp = probsum[t] * (1.0f / 32768.0f);
    sp[t] = pp * logf(pp + 1e-7f);
    __syncthreads();
    if (t < 256) {
        int seg = t >> 6;               // 0:sh g0, 1:sh g1, 2:sp g0, 3:sp g1
        int l = t & 63;
        const float* s = (seg & 2) ? sp : sh;
        int base = (seg & 1) * 320;
        float v = 0.f;
#pragma unroll
        for (int k = 0; k < 5; ++k) v += s[base + l + 64 * k];
#pragma unroll
        for (int off = 1; off < 64; off <<= 1) v += __shfl_xor(v, off);
        if (l == 0) sred[seg] = v;
    }
    __syncthreads();
    if (t < 2) out2[t] = expf(-sred[t * 2]) + expf(-sred[t * 2 + 1]);
}

extern "C" void kernel_launch(void* const* d_in, const int* in_sizes, int n_in,
                              void* d_out, int out_size, void* d_ws, size_t ws_size,
                              hipStream_t stream) {
    const float* x     = (const float*)d_in[0];   // [16,2048,768]
    const float* W     = (const float*)d_in[1];   // [768,640]
    const float* b     = (const float*)d_in[2];   // [640]
    const float* cb    = (const float*)d_in[3];   // [1,640,128]
    const float* noise = (const float*)d_in[4];   // [32768,2,320]
    float* out = (float*)d_out;                   // 16*2048*256 floats + 2 scalars

    char* ws = (char*)d_ws;
    unsigned* counts = (unsigned*)ws;             // [640] u32
    float* probsum   = (float*)(ws + 2560);       // [640] f32
    _Float16* WH     = (_Float16*)(ws + 8192);            // 24*40*64*8 halves = 983040 B
    _Float16* WL     = (_Float16*)(ws + 8192 + 983040);

    hipLaunchKernelGGL(prep_kernel, dim3(240), dim3(256), 0, stream, W, counts, WH, WL);
    hipLaunchKernelGGL(main_kernel, dim3(512), dim3(1024), 0, stream,
                       x, b, noise, cb, WH, WL, out, counts, probsum);
    hipLaunchKernelGGL(fin_kernel, dim3(1), dim3(640), 0, stream, counts, probsum, out + 8388608);
}